// Round 11
// baseline (506.293 us; speedup 1.0000x reference)
//
#include <hip/hip_runtime.h>
#include <math.h>

// ---------------- constants ----------------
#define N_NODES 20000
#define NPAD    20096          // 157*128
#define N_EDGES 200000
#define N_PAIRS 10000
#define PAIR_PAD 10368         // 162*64
#define DM_TILES 162
#define NBLK    79             // 79*256 = 20224 >= N_NODES

typedef __attribute__((ext_vector_type(8))) short s16x8;
typedef __attribute__((ext_vector_type(4))) float f32x4;

__device__ inline float wave_max(float v){
  for (int o = 32; o > 0; o >>= 1) v = fmaxf(v, __shfl_xor(v, o));
  return v;
}
__device__ inline float wave_sum(float v){
  for (int o = 32; o > 0; o >>= 1) v += __shfl_xor(v, o);
  return v;
}
__device__ inline short f2bf(float x){
  union { float f; unsigned u; } v; v.f = x;
  unsigned r = (v.u + 0x7FFFu + ((v.u >> 16) & 1u)) >> 16;
  return (short)r;
}
__device__ inline float bf2f(short s){
  union { unsigned u; float f; } v; v.u = ((unsigned)(unsigned short)s) << 16;
  return v.f;
}
__device__ inline int ntype(int s){ return (s < 8000) ? 0 : ((s < 14000) ? 1 : 2); }

// ---------------- input linears + ALL workspace zeroing + o_b slice 0 ----------------
__global__ void build_h(const float* __restrict__ f0, const float* __restrict__ w0, const float* __restrict__ b0,
                        const float* __restrict__ f1, const float* __restrict__ w1, const float* __restrict__ b1,
                        const float* __restrict__ f2, const float* __restrict__ w2, const float* __restrict__ b2,
                        short* __restrict__ Xb0, short* __restrict__ o_b,
                        int* __restrict__ csr_cnt, int* __restrict__ cnt5, int* __restrict__ pos5,
                        float* __restrict__ score, int* __restrict__ pairs,
                        float* __restrict__ eall, short* __restrict__ Xb12,
                        short* __restrict__ featb){
  int n = blockIdx.x, lane = threadIdx.x;
  int idx64 = n * 64 + lane;
  if (lane == 0) csr_cnt[n] = 0;
  if (n == 0 && lane < 5){ cnt5[lane * 16] = 0; pos5[lane * 16] = 0; }
  if (idx64 < 10016) score[idx64] = 0.f;
  if (idx64 < PAIR_PAD) pairs[idx64] = -1;
  if (idx64 < 480000) eall[idx64] = 0.f;
  s16x8 z = {};
  if (idx64 < 4608){
    int t = (idx64 * 16) / 24576, off = (idx64 * 16) % 24576;
    short* p = Xb12 + ((size_t)(t * NPAD + N_NODES)) * 256 + off;
    *(s16x8*)p = z; *(s16x8*)(p + 8) = z;
  }
  if (idx64 < 1152){
    int t = (idx64 * 16) / 6144, off = (idx64 * 16) % 6144;
    short* p = Xb0 + ((size_t)(t * NPAD + N_NODES)) * 64 + off;
    *(s16x8*)p = z; *(s16x8*)(p + 8) = z;
  }
  int t, idx, C; const float *f, *w, *b;
  if (n < 8000)       { t = 0; idx = n;         C = 256; f = f0; w = w0; b = b0; }
  else if (n < 14000) { t = 1; idx = n - 8000;  C = 128; f = f1; w = w1; b = b1; }
  else                { t = 2; idx = n - 14000; C = 64;  f = f2; w = w2; b = b2; }
  // zero off-slot feat_b for this node (layer-0 typed proj skips those tiles)
  {
    int h = lane >> 4, si = (lane >> 3) & 1, j8 = lane & 7;
    int s0 = (t == 0) ? 1 : 0;
    int s1 = (t == 2) ? 1 : 2;
    int toff = si ? s1 : s0;
    *(s16x8*)(featb + ((size_t)n * 4 + h) * 192 + toff * 64 + j8 * 8) = z;
  }
  __shared__ float xs[256];
  for (int c = lane; c < C; c += 64) xs[c] = f[(size_t)idx * C + c];
  __syncthreads();
  float acc = b[lane];
  for (int c = 0; c < C; c++) acc += xs[c] * w[c * 64 + lane];
  for (int tt = 0; tt < 3; tt++)
    Xb0[((size_t)(tt * NPAD) + n) * 64 + lane] = f2bf((tt == t) ? acc : 0.f);
  float ss = wave_sum(acc * acc);
  float sc = 1.f / fmaxf(sqrtf(ss), 1e-12f);
  for (int tt = 0; tt < 3; tt++)
    o_b[(size_t)n * 768 + tt * 256 + lane] = f2bf((tt == t) ? acc * sc : 0.f);
}

// ---------------- merged: edge/pair counting (blocks 0..781) + weight prep ----------------
__global__ void count_prep_k(const int* __restrict__ dst, int* __restrict__ csr_cnt,
                             const int* __restrict__ mid, int* __restrict__ cnt5,
                             const float* __restrict__ lW0, const float* __restrict__ lW1,
                             const float* __restrict__ lW2, const float* __restrict__ dmW,
                             short* __restrict__ Wt0, short* __restrict__ Wt1,
                             short* __restrict__ Wt2, short* __restrict__ Mt,
                             const float* __restrict__ ee0, const float* __restrict__ we0, const float* __restrict__ ae0,
                             const float* __restrict__ ee1, const float* __restrict__ we1, const float* __restrict__ ae1,
                             const float* __restrict__ ee2, const float* __restrict__ we2, const float* __restrict__ ae2,
                             float* __restrict__ ee5f){
  if (blockIdx.x < 782){
    int e = blockIdx.x * 256 + threadIdx.x;
    int lane = threadIdx.x & 63;
    if (e < N_EDGES) atomicAdd(&csr_cnt[dst[e]], 1);
    int r_mine = (e < N_PAIRS) ? mid[e] : -1;
#pragma unroll
    for (int r = 0; r < 5; r++){
      unsigned long long mask = __ballot(r_mine == r);
      if (mask){
        int leader = __ffsll((long long)mask) - 1;
        if (lane == leader) atomicAdd(&cnt5[r * 16], __popcll(mask));
      }
    }
    return;
  }
  int lin = blockIdx.x - 782;
  int z = lin / 576;
  int rem = lin % 576;
  int by = rem / 24, bx = rem % 24;
  if (z == 10){
    int r = bx, L = by;
    if (r >= 5 || L >= 3) return;
    int H = (L == 2) ? 1 : 4;
    const float* eetab = (L == 0) ? ee0 : ((L == 1) ? ee1 : ee2);
    const float* We    = (L == 0) ? we0 : ((L == 1) ? we1 : we2);
    const float* ae    = (L == 0) ? ae0 : ((L == 1) ? ae1 : ae2);
    int h = threadIdx.x >> 6, lane = threadIdx.x & 63;
    if (h >= H) return;
    float v = 0.f;
    for (int k = 0; k < 64; k++) v += eetab[r * 64 + k] * We[k * H * 64 + h * 64 + lane];
    v *= ae[h * 64 + lane];
    v = wave_sum(v);
    if (lane == 0) ee5f[L * 32 + r * H + h] = v;
    return;
  }
  const float* s; short* d; int R, Cc, r0, c0;
  if (z < 5){
    s = dmW + (size_t)z * 589824; d = Mt + (size_t)z * 589824;
    R = 768; Cc = 768; r0 = bx * 32; c0 = by * 32;
  } else if (z < 8){
    if (bx >= 8 || by >= 8) return;
    int t = z - 5;
    s = lW1 + (size_t)t * 65536; d = Wt1 + (size_t)t * 65536;
    R = 256; Cc = 256; r0 = bx * 32; c0 = by * 32;
  } else if (z == 8){
    if (bx >= 6 || by >= 8) return;
    int t = bx >> 1;
    s = lW0 + (size_t)t * 16384; d = Wt0 + (size_t)t * 16384;
    R = 64; Cc = 256; r0 = (bx & 1) * 32; c0 = by * 32;
  } else {
    if (bx >= 8 || by >= 6) return;
    int t = by >> 1;
    s = lW2 + (size_t)t * 16384; d = Wt2 + (size_t)t * 16384;
    R = 256; Cc = 64; r0 = bx * 32; c0 = (by & 1) * 32;
  }
  __shared__ float tile[32][33];
  int tx = threadIdx.x & 31, ty = threadIdx.x >> 5;
  for (int i = 0; i < 32; i += 8){
    int r = r0 + ty + i;
    tile[ty + i][tx] = (r < R && c0 + tx < Cc) ? s[(size_t)r * Cc + c0 + tx] : 0.f;
  }
  __syncthreads();
  for (int i = 0; i < 32; i += 8){
    int c = c0 + ty + i;
    if (c < Cc && r0 + tx < R)
      d[(size_t)c * R + r0 + tx] = f2bf(tile[tx][ty + i]);
  }
}

// ---------------- hierarchical scan ----------------
__global__ void scan1_k(const int* __restrict__ cnt, int* __restrict__ loc, int* __restrict__ bsum){
  __shared__ int s[256];
  int tid = threadIdx.x;
  int idx = blockIdx.x * 256 + tid;
  int v = (idx < N_NODES) ? cnt[idx] : 0;
  s[tid] = v;
  __syncthreads();
  for (int o = 1; o < 256; o <<= 1){
    int u = (tid >= o) ? s[tid - o] : 0;
    __syncthreads();
    s[tid] += u;
    __syncthreads();
  }
  if (idx < N_NODES) loc[idx] = s[tid] - v;
  if (tid == 255) bsum[blockIdx.x] = s[255];
}

__global__ void scan2_k(const int* __restrict__ bsum, int* __restrict__ bofs,
                        const int* __restrict__ cnt5, int* __restrict__ off5){
  __shared__ int s[128];
  int tid = threadIdx.x;
  int v = (tid < NBLK) ? bsum[tid] : 0;
  s[tid] = v;
  __syncthreads();
  for (int o = 1; o < 128; o <<= 1){
    int u = (tid >= o) ? s[tid - o] : 0;
    __syncthreads();
    s[tid] += u;
    __syncthreads();
  }
  if (tid < NBLK) bofs[tid] = s[tid] - v;
  if (tid == 0){
    int r0 = 0;
    for (int r = 0; r < 5; r++){ off5[r] = r0; r0 += ((cnt5[r * 16] + 63) >> 6) << 6; }
  }
}

__global__ void scan3_k(const int* __restrict__ loc, const int* __restrict__ bofs,
                        int* __restrict__ coff, int* __restrict__ cpos){
  int idx = blockIdx.x * 256 + threadIdx.x;
  if (idx < N_NODES){
    int v = loc[idx] + bofs[blockIdx.x];
    coff[idx] = v;
    cpos[idx * 16] = v;
  }
  if (idx == 0) coff[N_NODES] = N_EDGES;
}

__global__ void scatter_k(const int* __restrict__ dst, const int* __restrict__ srcv,
                          const int* __restrict__ efeat, int* __restrict__ cpos,
                          int* __restrict__ src_sorted, int* __restrict__ et_sorted,
                          const int* __restrict__ mid, const int* __restrict__ off5,
                          int* __restrict__ pos5, int* __restrict__ pairs){
  int e = blockIdx.x * 256 + threadIdx.x;
  int lane = threadIdx.x & 63;
  if (e < N_EDGES){
    int p = atomicAdd(&cpos[dst[e] * 16], 1);
    src_sorted[p] = srcv[e];
    et_sorted[p] = efeat[e];
  }
  int r_mine = (e < N_PAIRS) ? mid[e] : -1;
#pragma unroll
  for (int r = 0; r < 5; r++){
    unsigned long long mask = __ballot(r_mine == r);
    if (mask){
      int cnt = __popcll(mask);
      int leader = __ffsll((long long)mask) - 1;
      int base = 0;
      if (lane == leader) base = atomicAdd(&pos5[r * 16], cnt);
      base = __shfl(base, leader);
      if (r_mine == r){
        int rank = __popcll(mask & ((1ull << lane) - 1ull));
        pairs[off5[r] + base + rank] = e;
      }
    }
  }
}

// ---------------- MFMA slot projection -> bf16 feat + fused el/er partials ----------------
template<int C, int NO, int TYPED>
__global__ void mfma_proj(const short* __restrict__ Xb, const short* __restrict__ Wt,
                          short* __restrict__ featb, const float* __restrict__ al,
                          const float* __restrict__ ar, float* __restrict__ elf,
                          float* __restrict__ erf){
  constexpr int H = NO / 64;
  const int ct = blockIdx.y;
  const int t  = blockIdx.z;
  int tile = blockIdx.x;
  if (TYPED){
    const int lo[3] = {0, 62, 109};
    const int hi[3] = {63, 110, 157};
    tile += lo[t];
    if (tile >= hi[t]) return;
  }
  const int n0 = tile * 128;
  const int tid = threadIdx.x;
  const int w = tid >> 6, lane = tid & 63;
  const int quad = lane >> 4, ln = lane & 15;
  __shared__ __attribute__((aligned(16))) short A_s[128 * 32];
  __shared__ __attribute__((aligned(16))) short B_s[64 * 32];
  const short* Xt  = Xb + (size_t)t * NPAD * C;
  const short* Wtt = Wt + ((size_t)t * NO + ct * 64) * C;
  f32x4 acc[2][4] = {};
  for (int kk = 0; kk < C; kk += 32){
    {
      int row = tid >> 1, half = tid & 1;
      const s16x8* g = (const s16x8*)(Xt + (size_t)(n0 + row) * C + kk + half * 16);
      s16x8 v0 = g[0], v1 = g[1];
      *(s16x8*)(A_s + row * 32 + half * 16) = v0;
      *(s16x8*)(A_s + row * 32 + half * 16 + 8) = v1;
    }
    {
      int row = tid >> 2, chunk = tid & 3;
      s16x8 v = *(const s16x8*)(Wtt + (size_t)row * C + kk + chunk * 8);
      *(s16x8*)(B_s + row * 32 + chunk * 8) = v;
    }
    __syncthreads();
    s16x8 af0 = *(s16x8*)(A_s + (w * 32 + ln) * 32 + quad * 8);
    s16x8 af1 = *(s16x8*)(A_s + (w * 32 + 16 + ln) * 32 + quad * 8);
    s16x8 bf[4];
#pragma unroll
    for (int b = 0; b < 4; b++) bf[b] = *(s16x8*)(B_s + (b * 16 + ln) * 32 + quad * 8);
#pragma unroll
    for (int b = 0; b < 4; b++){
      acc[0][b] = __builtin_amdgcn_mfma_f32_16x16x32_bf16(af0, bf[b], acc[0][b], 0, 0, 0);
      acc[1][b] = __builtin_amdgcn_mfma_f32_16x16x32_bf16(af1, bf[b], acc[1][b], 0, 0, 0);
    }
    __syncthreads();
  }
#pragma unroll
  for (int ar_ = 0; ar_ < 2; ar_++){
#pragma unroll
    for (int i = 0; i < 4; i++){
      int n = n0 + w * 32 + ar_ * 16 + quad * 4 + i;
      if (n >= N_NODES) continue;
#pragma unroll
      for (int b = 0; b < 4; b++){
        int jj = b * 16 + ln;
        featb[((size_t)n * H + ct) * 192 + t * 64 + jj] = f2bf(acc[ar_][b][i]);
      }
    }
  }
  float alv[4], arv[4];
#pragma unroll
  for (int b = 0; b < 4; b++){
    alv[b] = al[ct * 192 + t * 64 + b * 16 + ln];
    arv[b] = ar[ct * 192 + t * 64 + b * 16 + ln];
  }
#pragma unroll
  for (int ar_ = 0; ar_ < 2; ar_++){
#pragma unroll
    for (int i = 0; i < 4; i++){
      float pe = 0.f, pr = 0.f;
#pragma unroll
      for (int b = 0; b < 4; b++){
        pe += acc[ar_][b][i] * alv[b];
        pr += acc[ar_][b][i] * arv[b];
      }
#pragma unroll
      for (int o = 1; o < 16; o <<= 1){
        pe += __shfl_xor(pe, o);
        pr += __shfl_xor(pr, o);
      }
      int n = n0 + w * 32 + ar_ * 16 + quad * 4 + i;
      if (ln == 0 && n < N_NODES){
        atomicAdd(&elf[n * H + ct], pe);
        atomicAdd(&erf[n * H + ct], pr);
      }
    }
  }
}

// ---------------- fused softmax + row-gather aggregation + emb (wave per node) ----------------
// STYPED=1 (layer 0): feat rows are slot-sparse (nonzero only slot==type(src));
// lanes skip loads whose slot mismatches -> 1/3 the fetch. Exact (skipped terms are zeros).
template<int H, int MODE, int ACT, int STYPED>
__global__ __launch_bounds__(256) void gat_fused(
    const int* __restrict__ csr_off, const int* __restrict__ src_sorted,
    const int* __restrict__ et_sorted,
    const float* __restrict__ el, const float* __restrict__ er, const float* __restrict__ ee5,
    const float* __restrict__ aprev, float* __restrict__ aout,
    const short* __restrict__ featb, short* __restrict__ outb,
    short* __restrict__ o_b, int kslice){
  const int wid = threadIdx.x >> 6, lane = threadIdx.x & 63;
  const int n = blockIdx.x * 4 + wid;
  if (n >= N_NODES) return;
  constexpr int NC = H * 192 / 8;
  const int c0 = lane, h0 = (c0 / 24) % H;
  const int c1 = lane + 64, h1 = (c1 / 24) % H;
  const int tl0 = (c0 % 24) >> 3;          // slot covered by chunk c0
  const int tl1 = (c1 % 24) >> 3;
  const bool act0 = (c0 < NC);
  const bool act1 = (H == 4) && (lane < 32);
  const int off = csr_off[n];
  const int cnt = csr_off[n + 1] - off;
  __shared__ float a_s[4][64][H];
  __shared__ float out_s[4][H * 192];
  float acc0[8] = {}, acc1[8] = {};
  float ern[H];
#pragma unroll
  for (int h = 0; h < H; h++) ern[h] = er[n * H + h];

  if (cnt > 0 && cnt <= 64){
    int p = off + lane;
    int sidx = 0, r = 0;
    if (lane < cnt){ sidx = src_sorted[p]; r = et_sorted[p]; }
    float lg[H];
#pragma unroll
    for (int h = 0; h < H; h++) lg[h] = -1e30f;
    if (lane < cnt){
#pragma unroll
      for (int h = 0; h < H; h++){
        float v = el[sidx * H + h] + ern[h] + ee5[r * H + h];
        lg[h] = (v >= 0.f) ? v : 0.2f * v;
      }
    }
    float ap[4] = {};
    if (MODE > 0 && lane < cnt){
#pragma unroll
      for (int q = 0; q < 4; q++) ap[q] = aprev[(size_t)p * 4 + q];
    }
    float av[H];
#pragma unroll
    for (int h = 0; h < H; h++){
      float mh = wave_max(lg[h]);
      float ex = (lane < cnt) ? __expf(lg[h] - mh) : 0.f;
      float sh = wave_sum(ex);
      float a = ex / sh;
      if (MODE == 1) a = 0.95f * a + 0.05f * ap[h];
      if (MODE == 2) a = 0.95f * a + 0.0125f * (ap[0] + ap[1] + ap[2] + ap[3]);
      av[h] = a;
      if (lane < cnt) a_s[wid][lane][h] = a;
    }
    if (MODE != 2 && lane < cnt){
      f32x4 o = {av[0], av[1], av[2], av[3]};
      *(f32x4*)(aout + (size_t)p * 4) = o;
    }
    int b = 0;
    for (; b + 4 <= cnt; b += 4){
      int p4 = off + b;
      int s0 = src_sorted[p4],     s1 = src_sorted[p4 + 1];
      int s2 = src_sorted[p4 + 2], s3 = src_sorted[p4 + 3];
      int ts0 = 0, ts1 = 0, ts2 = 0, ts3 = 0;
      if (STYPED){ ts0 = ntype(s0); ts1 = ntype(s1); ts2 = ntype(s2); ts3 = ntype(s3); }
      s16x8 v00 = {}, v01 = {}, v02 = {}, v03 = {}, v10 = {}, v11 = {}, v12 = {}, v13 = {};
      if (act0){
        if (!STYPED || tl0 == ts0) v00 = *(const s16x8*)(featb + (size_t)s0 * (H * 192) + c0 * 8);
        if (!STYPED || tl0 == ts1) v01 = *(const s16x8*)(featb + (size_t)s1 * (H * 192) + c0 * 8);
        if (!STYPED || tl0 == ts2) v02 = *(const s16x8*)(featb + (size_t)s2 * (H * 192) + c0 * 8);
        if (!STYPED || tl0 == ts3) v03 = *(const s16x8*)(featb + (size_t)s3 * (H * 192) + c0 * 8);
      }
      if (act1){
        if (!STYPED || tl1 == ts0) v10 = *(const s16x8*)(featb + (size_t)s0 * (H * 192) + c1 * 8);
        if (!STYPED || tl1 == ts1) v11 = *(const s16x8*)(featb + (size_t)s1 * (H * 192) + c1 * 8);
        if (!STYPED || tl1 == ts2) v12 = *(const s16x8*)(featb + (size_t)s2 * (H * 192) + c1 * 8);
        if (!STYPED || tl1 == ts3) v13 = *(const s16x8*)(featb + (size_t)s3 * (H * 192) + c1 * 8);
      }
      if (act0){
        float a0 = a_s[wid][b][h0], a1 = a_s[wid][b + 1][h0];
        float a2 = a_s[wid][b + 2][h0], a3 = a_s[wid][b + 3][h0];
#pragma unroll
        for (int i = 0; i < 8; i++)
          acc0[i] += a0 * bf2f(v00[i]) + a1 * bf2f(v01[i]) +
                     a2 * bf2f(v02[i]) + a3 * bf2f(v03[i]);
      }
      if (act1){
        float a0 = a_s[wid][b][h1], a1 = a_s[wid][b + 1][h1];
        float a2 = a_s[wid][b + 2][h1], a3 = a_s[wid][b + 3][h1];
#pragma unroll
        for (int i = 0; i < 8; i++)
          acc1[i] += a0 * bf2f(v10[i]) + a1 * bf2f(v11[i]) +
                     a2 * bf2f(v12[i]) + a3 * bf2f(v13[i]);
      }
    }
    for (; b < cnt; b++){
      int pp = off + b;
      int s = src_sorted[pp];
      int ts = STYPED ? ntype(s) : 0;
      if (act0 && (!STYPED || tl0 == ts)){
        float a = a_s[wid][b][h0];
        s16x8 v = *(const s16x8*)(featb + (size_t)s * (H * 192) + c0 * 8);
#pragma unroll
        for (int i = 0; i < 8; i++) acc0[i] += a * bf2f(v[i]);
      }
      if (act1 && (!STYPED || tl1 == ts)){
        float a = a_s[wid][b][h1];
        s16x8 v = *(const s16x8*)(featb + (size_t)s * (H * 192) + c1 * 8);
#pragma unroll
        for (int i = 0; i < 8; i++) acc1[i] += a * bf2f(v[i]);
      }
    }
  } else if (cnt > 64){
    float mh[H], sh[H];
#pragma unroll
    for (int h = 0; h < H; h++){ mh[h] = -1e30f; sh[h] = 0.f; }
    for (int b = lane; b < cnt; b += 64){
      int p = off + b; int s = src_sorted[p]; int r = et_sorted[p];
#pragma unroll
      for (int h = 0; h < H; h++){
        float v = el[s * H + h] + ern[h] + ee5[r * H + h];
        v = (v >= 0.f) ? v : 0.2f * v;
        mh[h] = fmaxf(mh[h], v);
      }
    }
#pragma unroll
    for (int h = 0; h < H; h++) mh[h] = wave_max(mh[h]);
    for (int b = lane; b < cnt; b += 64){
      int p = off + b; int s = src_sorted[p]; int r = et_sorted[p];
#pragma unroll
      for (int h = 0; h < H; h++){
        float v = el[s * H + h] + ern[h] + ee5[r * H + h];
        v = (v >= 0.f) ? v : 0.2f * v;
        sh[h] += __expf(v - mh[h]);
      }
    }
#pragma unroll
    for (int h = 0; h < H; h++) sh[h] = wave_sum(sh[h]);
    if (MODE != 2){
      for (int b = lane; b < cnt; b += 64){
        int p = off + b; int s = src_sorted[p]; int r = et_sorted[p];
        float ap[4] = {};
        if (MODE > 0){
#pragma unroll
          for (int q = 0; q < 4; q++) ap[q] = aprev[(size_t)p * 4 + q];
        }
        float av[4] = {};
#pragma unroll
        for (int h = 0; h < H; h++){
          float v = el[s * H + h] + ern[h] + ee5[r * H + h];
          v = (v >= 0.f) ? v : 0.2f * v;
          float a = __expf(v - mh[h]) / sh[h];
          if (MODE == 1) a = 0.95f * a + 0.05f * ap[h];
          av[h] = a;
        }
        f32x4 o = {av[0], av[1], av[2], av[3]};
        *(f32x4*)(aout + (size_t)p * 4) = o;
      }
    }
    for (int b = 0; b < cnt; b++){
      int p = off + b; int s = src_sorted[p]; int r = et_sorted[p];
      const short* row = featb + (size_t)s * (H * 192);
      float apm[4] = {};
      if (MODE > 0){
#pragma unroll
        for (int q = 0; q < 4; q++) apm[q] = aprev[(size_t)p * 4 + q];
      }
      if (act0){
        float v = el[s * H + h0] + ern[h0] + ee5[r * H + h0];
        v = (v >= 0.f) ? v : 0.2f * v;
        float a = __expf(v - mh[h0]) / sh[h0];
        if (MODE == 1) a = 0.95f * a + 0.05f * apm[h0];
        if (MODE == 2) a = 0.95f * a + 0.0125f * (apm[0] + apm[1] + apm[2] + apm[3]);
        s16x8 vv = *(const s16x8*)(row + c0 * 8);
#pragma unroll
        for (int i = 0; i < 8; i++) acc0[i] += a * bf2f(vv[i]);
      }
      if (act1){
        float v = el[s * H + h1] + ern[h1] + ee5[r * H + h1];
        v = (v >= 0.f) ? v : 0.2f * v;
        float a = __expf(v - mh[h1]) / sh[h1];
        if (MODE == 1) a = 0.95f * a + 0.05f * apm[h1];
        s16x8 vv = *(const s16x8*)(row + c1 * 8);
#pragma unroll
        for (int i = 0; i < 8; i++) acc1[i] += a * bf2f(vv[i]);
      }
    }
  }
  // ---- epilogue ----
  if (act0){
    int dd = c0 * 8, h = dd / 192, rr = dd % 192, t = rr / 64, j = rr % 64;
    if (ACT){
#pragma unroll
      for (int i = 0; i < 8; i++) acc0[i] = (acc0[i] > 0.f) ? acc0[i] : expm1f(acc0[i]);
    }
#pragma unroll
    for (int i = 0; i < 8; i++) out_s[wid][dd + i] = acc0[i];
    if (outb){
      s16x8 o;
#pragma unroll
      for (int i = 0; i < 8; i++) o[i] = f2bf(acc0[i]);
      *(s16x8*)(outb + ((size_t)(t * NPAD) + n) * 256 + h * 64 + j) = o;
    }
  }
  if (act1){
    int dd = c1 * 8, h = dd / 192, rr = dd % 192, t = rr / 64, j = rr % 64;
    if (ACT){
#pragma unroll
      for (int i = 0; i < 8; i++) acc1[i] = (acc1[i] > 0.f) ? acc1[i] : expm1f(acc1[i]);
    }
#pragma unroll
    for (int i = 0; i < 8; i++) out_s[wid][dd + i] = acc1[i];
    if (outb){
      s16x8 o;
#pragma unroll
      for (int i = 0; i < 8; i++) o[i] = f2bf(acc1[i]);
      *(s16x8*)(outb + ((size_t)(t * NPAD) + n) * 256 + h * 64 + j) = o;
    }
  }
  for (int t = 0; t < 3; t++){
    float v;
    if (H == 4)
      v = 0.25f * (out_s[wid][t * 64 + lane] + out_s[wid][192 + t * 64 + lane] +
                   out_s[wid][384 + t * 64 + lane] + out_s[wid][576 + t * 64 + lane]);
    else
      v = out_s[wid][t * 64 + lane];
    float ss = wave_sum(v * v);
    float sc = 1.f / fmaxf(sqrtf(ss), 1e-12f);
    o_b[(size_t)n * 768 + t * 256 + kslice * 64 + lane] = f2bf(v * sc);
  }
}

// ---------------- DistMult via MFMA ----------------
__global__ void distmult_mfma(const short* __restrict__ o_b, const short* __restrict__ Mt,
                              const int* __restrict__ pairs, const int* __restrict__ left,
                              const int* __restrict__ right, const int* __restrict__ mid,
                              float* __restrict__ score){
  const int pt = blockIdx.x, ct = blockIdx.y;
  const int tid = threadIdx.x;
  const int w = tid >> 6, lane = tid & 63;
  const int quad = lane >> 4, ln = lane & 15;
  __shared__ __attribute__((aligned(16))) short smem[8192];
  short* A_s = smem;
  short* B_s = smem + 2048;
  __shared__ int pid_s[64];
  __shared__ int lbase[64];
  if (tid < 64){
    int p = pairs[pt * 64 + tid];
    pid_s[tid] = p;
    lbase[tid] = (p >= 0) ? left[p] * 768 : 0;
  }
  __syncthreads();
  int p0 = pid_s[0];
  if (p0 < 0) return;
  const int r = mid[p0];
  const short* Mr = Mt + (size_t)r * 768 * 768;
  f32x4 acc[8] = {};
  for (int kk = 0; kk < 768; kk += 32){
    {
      int row = tid >> 2, chunk = tid & 3;
      s16x8 v = *(const s16x8*)(o_b + (size_t)lbase[row] + kk + chunk * 8);
      *(s16x8*)(A_s + row * 32 + chunk * 8) = v;
    }
    {
      int row = tid >> 1, half = tid & 1;
      const s16x8* g = (const s16x8*)(Mr + (size_t)(ct * 128 + row) * 768 + kk + half * 16);
      s16x8 v0 = g[0], v1 = g[1];
      *(s16x8*)(B_s + row * 32 + half * 16) = v0;
      *(s16x8*)(B_s + row * 32 + half * 16 + 8) = v1;
    }
    __syncthreads();
    s16x8 af = *(s16x8*)(A_s + (w * 16 + ln) * 32 + quad * 8);
#pragma unroll
    for (int b = 0; b < 8; b++){
      s16x8 bf = *(s16x8*)(B_s + (b * 16 + ln) * 32 + quad * 8);
      acc[b] = __builtin_amdgcn_mfma_f32_16x16x32_bf16(af, bf, acc[b], 0, 0, 0);
    }
    __syncthreads();
  }
  short* RE_s = smem;
  {
    int row = tid >> 2, quarter = tid & 3;
    int p = pid_s[row];
    s16x8 v0 = {}, v1 = {}, v2 = {}, v3 = {};
    if (p >= 0){
      const s16x8* g = (const s16x8*)(o_b + (size_t)right[p] * 768 + ct * 128 + quarter * 32);
      v0 = g[0]; v1 = g[1]; v2 = g[2]; v3 = g[3];
    }
    __syncthreads();
    short* dst = RE_s + row * 128 + quarter * 32;
    *(s16x8*)(dst)      = v0;
    *(s16x8*)(dst + 8)  = v1;
    *(s16x8*)(dst + 16) = v2;
    *(s16x8*)(dst + 24) = v3;
  }
  __syncthreads();
#pragma unroll
  for (int i = 0; i < 4; i++){
    int row = w * 16 + quad * 4 + i;
    float s = 0.f;
#pragma unroll
    for (int b = 0; b < 8; b++)
      s += acc[b][i] * bf2f(RE_s[row * 128 + b * 16 + ln]);
    s += __shfl_xor(s, 1); s += __shfl_xor(s, 2);
    s += __shfl_xor(s, 4); s += __shfl_xor(s, 8);
    if (ln == 0){
      int p = pid_s[row];
      if (p >= 0) atomicAdd(&score[p], s);
    }
  }
}

__global__ void sigmoid_k(const float* __restrict__ score, float* __restrict__ out){
  int i = blockIdx.x * 256 + threadIdx.x;
  if (i < N_PAIRS) out[i] = 1.f / (1.f + __expf(-score[i]));
}

// ---------------- launcher ----------------
extern "C" void kernel_launch(void* const* d_in, const int* in_sizes, int n_in,
                              void* d_out, int out_size, void* d_ws, size_t ws_size,
                              hipStream_t stream){
  const float* f0 = (const float*)d_in[0];
  const float* w0 = (const float*)d_in[1];
  const float* b0 = (const float*)d_in[2];
  const float* f1 = (const float*)d_in[3];
  const float* w1 = (const float*)d_in[4];
  const float* b1 = (const float*)d_in[5];
  const float* f2 = (const float*)d_in[6];
  const float* w2_ = (const float*)d_in[7];
  const float* b2 = (const float*)d_in[8];
  const float* lW[3]  = {(const float*)d_in[9],  (const float*)d_in[15], (const float*)d_in[21]};
  const float* lal[3] = {(const float*)d_in[10], (const float*)d_in[16], (const float*)d_in[22]};
  const float* lar[3] = {(const float*)d_in[11], (const float*)d_in[17], (const float*)d_in[23]};
  const float* lee[3] = {(const float*)d_in[12], (const float*)d_in[18], (const float*)d_in[24]};
  const float* lwe[3] = {(const float*)d_in[13], (const float*)d_in[19], (const float*)d_in[25]};
  const float* lae[3] = {(const float*)d_in[14], (const float*)d_in[20], (const float*)d_in[26]};
  const float* dmW = (const float*)d_in[27];
  const int* efeat = (const int*)d_in[28];
  const int* srcv  = (const int*)d_in[29];
  const int* dstv  = (const int*)d_in[30];
  const int* left  = (const int*)d_in[31];
  const int* right = (const int*)d_in[32];
  const int* midv  = (const int*)d_in[33];
  float* out = (float*)d_out;

  // ---- workspace layout ----
  short* feat_b = (short*)d_ws;               // 15,360,000 shorts
  float* aA     = (float*)(feat_b + 15360000);// 800,000
  float* aB     = aA + 800000;                // 800,000
  float* eall   = aB + 800000;                // 480,000
  float* ee5f   = eall + 480000;              // 96
  float* score  = ee5f + 96;                  // 10,016
  int* csr_cnt  = (int*)(score + 10016);      // 20,000
  int* csr_off  = csr_cnt + 20000;            // 20,004
  int* csr_pos  = csr_off + 20004;            // 320,000 (padded x16)
  int* loc      = csr_pos + 320000;           // 20,000
  int* bsum     = loc + 20000;                // 128
  int* bofs     = bsum + 128;                 // 128
  int* src_sorted = bofs + 128;               // 200,000
  int* et_sorted  = src_sorted + 200000;      // 200,000
  int* cnt5     = et_sorted + 200000;         // 80
  int* off5     = cnt5 + 80;                  // 8
  int* pos5     = off5 + 8;                   // 80
  int* pairs    = pos5 + 80;                  // 10,368
  short* o_b    = (short*)(pairs + PAIR_PAD); // 15,360,000
  short* Xb0    = o_b + 15360000;             // 3,858,432
  short* Xb12   = Xb0 + 3858432;              // 15,433,728
  short* Wt0    = Xb12 + 15433728;            // 49,152
  short* Wt1    = Wt0 + 49152;                // 196,608
  short* Wt2    = Wt1 + 196608;               // 49,152
  short* Mt     = Wt2 + 49152;                // 2,949,120
  float* elf0 = eall, *erf0 = eall + 80000;
  float* elf1 = eall + 160000, *erf1 = eall + 240000;
  float* elf2 = eall + 320000, *erf2 = eall + 400000;

  build_h<<<N_NODES, 64, 0, stream>>>(f0, w0, b0, f1, w1, b1, f2, w2_, b2, Xb0, o_b,
                                      csr_cnt, cnt5, pos5, score, pairs, eall, Xb12, feat_b);
  count_prep_k<<<782 + 6336, 256, 0, stream>>>(dstv, csr_cnt, midv, cnt5,
                                               lW[0], lW[1], lW[2], dmW, Wt0, Wt1, Wt2, Mt,
                                               lee[0], lwe[0], lae[0], lee[1], lwe[1], lae[1],
                                               lee[2], lwe[2], lae[2], ee5f);
  scan1_k<<<NBLK, 256, 0, stream>>>(csr_cnt, loc, bsum);
  scan2_k<<<1, 128, 0, stream>>>(bsum, bofs, cnt5, off5);
  scan3_k<<<NBLK, 256, 0, stream>>>(loc, bofs, csr_off, csr_pos);
  scatter_k<<<782, 256, 0, stream>>>(dstv, srcv, efeat, csr_pos, src_sorted, et_sorted,
                                     midv, off5, pos5, pairs);

  // layer 0 (H=4, typed tiles + typed gather, ELU) -> emb slice 1
  { dim3 g(64, 4, 3);
    mfma_proj<64, 256, 1><<<g, 256, 0, stream>>>(Xb0, Wt0, feat_b, lal[0], lar[0], elf0, erf0); }
  gat_fused<4, 0, 1, 1><<<5000, 256, 0, stream>>>(csr_off, src_sorted, et_sorted, elf0, erf0, ee5f,
                                                  nullptr, aA, feat_b, Xb12, o_b, 1);

  // layer 1 (H=4, residual aA, ELU) -> emb slice 2
  { dim3 g(NPAD / 128, 4, 3);
    mfma_proj<256, 256, 0><<<g, 256, 0, stream>>>(Xb12, Wt1, feat_b, lal[1], lar[1], elf1, erf1); }
  gat_fused<4, 1, 1, 0><<<5000, 256, 0, stream>>>(csr_off, src_sorted, et_sorted, elf1, erf1, ee5f + 32,
                                                  aA, aB, feat_b, Xb12, o_b, 2);

  // layer 2 (H=1, blend vs mean of a1, no activation) -> emb slice 3
  { dim3 g(NPAD / 128, 1, 3);
    mfma_proj<256, 64, 0><<<g, 256, 0, stream>>>(Xb12, Wt2, feat_b, lal[2], lar[2], elf2, erf2); }
  gat_fused<1, 2, 0, 0><<<5000, 256, 0, stream>>>(csr_off, src_sorted, et_sorted, elf2, erf2, ee5f + 64,
                                                  aB, nullptr, feat_b, nullptr, o_b, 3);

  // DistMult + sigmoid
  { dim3 g(DM_TILES, 6); distmult_mfma<<<g, 256, 0, stream>>>(o_b, Mt, pairs, left, right, midv, score); }
  sigmoid_k<<<40, 256, 0, stream>>>(score, out);
}

// Round 12
// 502.175 us; speedup vs baseline: 1.0082x; 1.0082x over previous
//
#include <hip/hip_runtime.h>
#include <math.h>

// ---------------- constants ----------------
#define N_NODES 20000
#define NPAD    20096          // 157*128
#define N_EDGES 200000
#define N_PAIRS 10000
#define PAIR_PAD 10368         // 162*64
#define DM_TILES 162
#define NBLK    79             // 79*256 = 20224 >= N_NODES

typedef __attribute__((ext_vector_type(8))) short s16x8;
typedef __attribute__((ext_vector_type(4))) float f32x4;

__device__ inline float wave_max(float v){
  for (int o = 32; o > 0; o >>= 1) v = fmaxf(v, __shfl_xor(v, o));
  return v;
}
__device__ inline float wave_sum(float v){
  for (int o = 32; o > 0; o >>= 1) v += __shfl_xor(v, o);
  return v;
}
__device__ inline short f2bf(float x){
  union { float f; unsigned u; } v; v.f = x;
  unsigned r = (v.u + 0x7FFFu + ((v.u >> 16) & 1u)) >> 16;
  return (short)r;
}
__device__ inline float bf2f(short s){
  union { unsigned u; float f; } v; v.u = ((unsigned)(unsigned short)s) << 16;
  return v.f;
}

// ---------------- input linears (8 nodes/block) + ALL workspace zeroing + o_b slice 0 ----------------
// blocks 0..999: type0 (C=256); 1000..1749: type1 (C=128); 1750..2499: type2 (C=64).
// 8000 and 14000 are multiples of 8 -> blocks never span a type boundary.
__global__ void build_h(const float* __restrict__ f0, const float* __restrict__ w0, const float* __restrict__ b0,
                        const float* __restrict__ f1, const float* __restrict__ w1, const float* __restrict__ b1,
                        const float* __restrict__ f2, const float* __restrict__ w2, const float* __restrict__ b2,
                        short* __restrict__ Xb0, short* __restrict__ o_b,
                        int* __restrict__ csr_cnt, int* __restrict__ cnt5, int* __restrict__ pos5,
                        float* __restrict__ score, int* __restrict__ pairs,
                        float* __restrict__ eall, short* __restrict__ Xb12,
                        short* __restrict__ featb){
  const int blk = blockIdx.x, lane = threadIdx.x;
  const int gid = blk * 64 + lane;             // 0..159999
  // ---- zeroing (spread across grid) ----
  if (gid < N_NODES) csr_cnt[gid] = 0;
  if (gid < 5){ cnt5[gid * 16] = 0; pos5[gid * 16] = 0; }
  if (gid < 10016) score[gid] = 0.f;
  if (gid < PAIR_PAD) pairs[gid] = -1;
  for (int i = gid; i < 480000; i += 160000) eall[i] = 0.f;
  s16x8 z = {};
  if (gid < 4608){  // Xb12 pad rows: 3 * 96 * 256 shorts
    int t = (gid * 16) / 24576, off = (gid * 16) % 24576;
    short* p = Xb12 + ((size_t)(t * NPAD + N_NODES)) * 256 + off;
    *(s16x8*)p = z; *(s16x8*)(p + 8) = z;
  }
  if (gid < 1152){  // Xb0 pad rows
    int t = (gid * 16) / 6144, off = (gid * 16) % 6144;
    short* p = Xb0 + ((size_t)(t * NPAD + N_NODES)) * 64 + off;
    *(s16x8*)p = z; *(s16x8*)(p + 8) = z;
  }
  // ---- per-block type ----
  int t, C, nbase; const float *f, *w, *b;
  if (blk < 1000)       { t = 0; nbase = 0;     C = 256; f = f0; w = w0; b = b0; }
  else if (blk < 1750)  { t = 1; nbase = 8000;  C = 128; f = f1; w = w1; b = b1; }
  else                  { t = 2; nbase = 14000; C = 64;  f = f2; w = w2; b = b2; }
  const int n0 = blk * 8;                       // first node of this block
  const int n0l = n0 - nbase;                   // local row in f
  // ---- stage 8 input rows (contiguous) ----
  __shared__ float xs[8 * 256];
  const float* fr = f + (size_t)n0l * C;
  for (int i = lane; i < 8 * C; i += 64) xs[i] = fr[i];
  __syncthreads();
  // ---- 8 dots per lane, sharing each w load ----
  float acc[8];
#pragma unroll
  for (int j = 0; j < 8; j++) acc[j] = b[lane];
  for (int c = 0; c < C; c++){
    float wv = w[c * 64 + lane];
#pragma unroll
    for (int j = 0; j < 8; j++) acc[j] += xs[j * C + c] * wv;
  }
  // ---- per-node epilogue ----
  for (int j = 0; j < 8; j++){
    int n = n0 + j;
    // off-slot feat_b zero (layer-0 typed proj skips those tiles; untyped gather reads them)
    {
      int h = lane >> 4, si = (lane >> 3) & 1, j8 = lane & 7;
      int s0 = (t == 0) ? 1 : 0;
      int s1 = (t == 2) ? 1 : 2;
      int toff = si ? s1 : s0;
      *(s16x8*)(featb + ((size_t)n * 4 + h) * 192 + toff * 64 + j8 * 8) = z;
    }
    for (int tt = 0; tt < 3; tt++)
      Xb0[((size_t)(tt * NPAD) + n) * 64 + lane] = f2bf((tt == t) ? acc[j] : 0.f);
    float ss = wave_sum(acc[j] * acc[j]);
    float sc = 1.f / fmaxf(sqrtf(ss), 1e-12f);
    for (int tt = 0; tt < 3; tt++)
      o_b[(size_t)n * 768 + tt * 256 + lane] = f2bf((tt == t) ? acc[j] * sc : 0.f);
  }
}

// ---------------- merged: edge/pair counting (blocks 0..781) + weight prep ----------------
__global__ void count_prep_k(const int* __restrict__ dst, int* __restrict__ csr_cnt,
                             const int* __restrict__ mid, int* __restrict__ cnt5,
                             const float* __restrict__ lW0, const float* __restrict__ lW1,
                             const float* __restrict__ lW2, const float* __restrict__ dmW,
                             short* __restrict__ Wt0, short* __restrict__ Wt1,
                             short* __restrict__ Wt2, short* __restrict__ Mt,
                             const float* __restrict__ ee0, const float* __restrict__ we0, const float* __restrict__ ae0,
                             const float* __restrict__ ee1, const float* __restrict__ we1, const float* __restrict__ ae1,
                             const float* __restrict__ ee2, const float* __restrict__ we2, const float* __restrict__ ae2,
                             float* __restrict__ ee5f){
  if (blockIdx.x < 782){
    int e = blockIdx.x * 256 + threadIdx.x;
    int lane = threadIdx.x & 63;
    if (e < N_EDGES) atomicAdd(&csr_cnt[dst[e]], 1);
    int r_mine = (e < N_PAIRS) ? mid[e] : -1;
#pragma unroll
    for (int r = 0; r < 5; r++){
      unsigned long long mask = __ballot(r_mine == r);
      if (mask){
        int leader = __ffsll((long long)mask) - 1;
        if (lane == leader) atomicAdd(&cnt5[r * 16], __popcll(mask));
      }
    }
    return;
  }
  int lin = blockIdx.x - 782;
  int z = lin / 576;
  int rem = lin % 576;
  int by = rem / 24, bx = rem % 24;
  if (z == 10){
    int r = bx, L = by;
    if (r >= 5 || L >= 3) return;
    int H = (L == 2) ? 1 : 4;
    const float* eetab = (L == 0) ? ee0 : ((L == 1) ? ee1 : ee2);
    const float* We    = (L == 0) ? we0 : ((L == 1) ? we1 : we2);
    const float* ae    = (L == 0) ? ae0 : ((L == 1) ? ae1 : ae2);
    int h = threadIdx.x >> 6, lane = threadIdx.x & 63;
    if (h >= H) return;
    float v = 0.f;
    for (int k = 0; k < 64; k++) v += eetab[r * 64 + k] * We[k * H * 64 + h * 64 + lane];
    v *= ae[h * 64 + lane];
    v = wave_sum(v);
    if (lane == 0) ee5f[L * 32 + r * H + h] = v;
    return;
  }
  const float* s; short* d; int R, Cc, r0, c0;
  if (z < 5){
    s = dmW + (size_t)z * 589824; d = Mt + (size_t)z * 589824;
    R = 768; Cc = 768; r0 = bx * 32; c0 = by * 32;
  } else if (z < 8){
    if (bx >= 8 || by >= 8) return;
    int t = z - 5;
    s = lW1 + (size_t)t * 65536; d = Wt1 + (size_t)t * 65536;
    R = 256; Cc = 256; r0 = bx * 32; c0 = by * 32;
  } else if (z == 8){
    if (bx >= 6 || by >= 8) return;
    int t = bx >> 1;
    s = lW0 + (size_t)t * 16384; d = Wt0 + (size_t)t * 16384;
    R = 64; Cc = 256; r0 = (bx & 1) * 32; c0 = by * 32;
  } else {
    if (bx >= 8 || by >= 6) return;
    int t = by >> 1;
    s = lW2 + (size_t)t * 16384; d = Wt2 + (size_t)t * 16384;
    R = 256; Cc = 64; r0 = bx * 32; c0 = (by & 1) * 32;
  }
  __shared__ float tile[32][33];
  int tx = threadIdx.x & 31, ty = threadIdx.x >> 5;
  for (int i = 0; i < 32; i += 8){
    int r = r0 + ty + i;
    tile[ty + i][tx] = (r < R && c0 + tx < Cc) ? s[(size_t)r * Cc + c0 + tx] : 0.f;
  }
  __syncthreads();
  for (int i = 0; i < 32; i += 8){
    int c = c0 + ty + i;
    if (c < Cc && r0 + tx < R)
      d[(size_t)c * R + r0 + tx] = f2bf(tile[tx][ty + i]);
  }
}

// ---------------- hierarchical scan ----------------
__global__ void scan1_k(const int* __restrict__ cnt, int* __restrict__ loc, int* __restrict__ bsum){
  __shared__ int s[256];
  int tid = threadIdx.x;
  int idx = blockIdx.x * 256 + tid;
  int v = (idx < N_NODES) ? cnt[idx] : 0;
  s[tid] = v;
  __syncthreads();
  for (int o = 1; o < 256; o <<= 1){
    int u = (tid >= o) ? s[tid - o] : 0;
    __syncthreads();
    s[tid] += u;
    __syncthreads();
  }
  if (idx < N_NODES) loc[idx] = s[tid] - v;
  if (tid == 255) bsum[blockIdx.x] = s[255];
}

__global__ void scan2_k(const int* __restrict__ bsum, int* __restrict__ bofs,
                        const int* __restrict__ cnt5, int* __restrict__ off5){
  __shared__ int s[128];
  int tid = threadIdx.x;
  int v = (tid < NBLK) ? bsum[tid] : 0;
  s[tid] = v;
  __syncthreads();
  for (int o = 1; o < 128; o <<= 1){
    int u = (tid >= o) ? s[tid - o] : 0;
    __syncthreads();
    s[tid] += u;
    __syncthreads();
  }
  if (tid < NBLK) bofs[tid] = s[tid] - v;
  if (tid == 0){
    int r0 = 0;
    for (int r = 0; r < 5; r++){ off5[r] = r0; r0 += ((cnt5[r * 16] + 63) >> 6) << 6; }
  }
}

__global__ void scan3_k(const int* __restrict__ loc, const int* __restrict__ bofs,
                        int* __restrict__ coff, int* __restrict__ cpos){
  int idx = blockIdx.x * 256 + threadIdx.x;
  if (idx < N_NODES){
    int v = loc[idx] + bofs[blockIdx.x];
    coff[idx] = v;
    cpos[idx * 16] = v;
  }
  if (idx == 0) coff[N_NODES] = N_EDGES;
}

__global__ void scatter_k(const int* __restrict__ dst, const int* __restrict__ srcv,
                          const int* __restrict__ efeat, int* __restrict__ cpos,
                          int* __restrict__ src_sorted, int* __restrict__ et_sorted,
                          const int* __restrict__ mid, const int* __restrict__ off5,
                          int* __restrict__ pos5, int* __restrict__ pairs){
  int e = blockIdx.x * 256 + threadIdx.x;
  int lane = threadIdx.x & 63;
  if (e < N_EDGES){
    int p = atomicAdd(&cpos[dst[e] * 16], 1);
    src_sorted[p] = srcv[e];
    et_sorted[p] = efeat[e];
  }
  int r_mine = (e < N_PAIRS) ? mid[e] : -1;
#pragma unroll
  for (int r = 0; r < 5; r++){
    unsigned long long mask = __ballot(r_mine == r);
    if (mask){
      int cnt = __popcll(mask);
      int leader = __ffsll((long long)mask) - 1;
      int base = 0;
      if (lane == leader) base = atomicAdd(&pos5[r * 16], cnt);
      base = __shfl(base, leader);
      if (r_mine == r){
        int rank = __popcll(mask & ((1ull << lane) - 1ull));
        pairs[off5[r] + base + rank] = e;
      }
    }
  }
}

// ---------------- MFMA slot projection -> bf16 feat + fused el/er partials ----------------
template<int C, int NO, int TYPED>
__global__ void mfma_proj(const short* __restrict__ Xb, const short* __restrict__ Wt,
                          short* __restrict__ featb, const float* __restrict__ al,
                          const float* __restrict__ ar, float* __restrict__ elf,
                          float* __restrict__ erf){
  constexpr int H = NO / 64;
  const int ct = blockIdx.y;
  const int t  = blockIdx.z;
  int tile = blockIdx.x;
  if (TYPED){
    const int lo[3] = {0, 62, 109};
    const int hi[3] = {63, 110, 157};
    tile += lo[t];
    if (tile >= hi[t]) return;
  }
  const int n0 = tile * 128;
  const int tid = threadIdx.x;
  const int w = tid >> 6, lane = tid & 63;
  const int quad = lane >> 4, ln = lane & 15;
  __shared__ __attribute__((aligned(16))) short A_s[128 * 32];
  __shared__ __attribute__((aligned(16))) short B_s[64 * 32];
  const short* Xt  = Xb + (size_t)t * NPAD * C;
  const short* Wtt = Wt + ((size_t)t * NO + ct * 64) * C;
  f32x4 acc[2][4] = {};
  for (int kk = 0; kk < C; kk += 32){
    {
      int row = tid >> 1, half = tid & 1;
      const s16x8* g = (const s16x8*)(Xt + (size_t)(n0 + row) * C + kk + half * 16);
      s16x8 v0 = g[0], v1 = g[1];
      *(s16x8*)(A_s + row * 32 + half * 16) = v0;
      *(s16x8*)(A_s + row * 32 + half * 16 + 8) = v1;
    }
    {
      int row = tid >> 2, chunk = tid & 3;
      s16x8 v = *(const s16x8*)(Wtt + (size_t)row * C + kk + chunk * 8);
      *(s16x8*)(B_s + row * 32 + chunk * 8) = v;
    }
    __syncthreads();
    s16x8 af0 = *(s16x8*)(A_s + (w * 32 + ln) * 32 + quad * 8);
    s16x8 af1 = *(s16x8*)(A_s + (w * 32 + 16 + ln) * 32 + quad * 8);
    s16x8 bf[4];
#pragma unroll
    for (int b = 0; b < 4; b++) bf[b] = *(s16x8*)(B_s + (b * 16 + ln) * 32 + quad * 8);
#pragma unroll
    for (int b = 0; b < 4; b++){
      acc[0][b] = __builtin_amdgcn_mfma_f32_16x16x32_bf16(af0, bf[b], acc[0][b], 0, 0, 0);
      acc[1][b] = __builtin_amdgcn_mfma_f32_16x16x32_bf16(af1, bf[b], acc[1][b], 0, 0, 0);
    }
    __syncthreads();
  }
#pragma unroll
  for (int ar_ = 0; ar_ < 2; ar_++){
#pragma unroll
    for (int i = 0; i < 4; i++){
      int n = n0 + w * 32 + ar_ * 16 + quad * 4 + i;
      if (n >= N_NODES) continue;
#pragma unroll
      for (int b = 0; b < 4; b++){
        int jj = b * 16 + ln;
        featb[((size_t)n * H + ct) * 192 + t * 64 + jj] = f2bf(acc[ar_][b][i]);
      }
    }
  }
  float alv[4], arv[4];
#pragma unroll
  for (int b = 0; b < 4; b++){
    alv[b] = al[ct * 192 + t * 64 + b * 16 + ln];
    arv[b] = ar[ct * 192 + t * 64 + b * 16 + ln];
  }
#pragma unroll
  for (int ar_ = 0; ar_ < 2; ar_++){
#pragma unroll
    for (int i = 0; i < 4; i++){
      float pe = 0.f, pr = 0.f;
#pragma unroll
      for (int b = 0; b < 4; b++){
        pe += acc[ar_][b][i] * alv[b];
        pr += acc[ar_][b][i] * arv[b];
      }
#pragma unroll
      for (int o = 1; o < 16; o <<= 1){
        pe += __shfl_xor(pe, o);
        pr += __shfl_xor(pr, o);
      }
      int n = n0 + w * 32 + ar_ * 16 + quad * 4 + i;
      if (ln == 0 && n < N_NODES){
        atomicAdd(&elf[n * H + ct], pe);
        atomicAdd(&erf[n * H + ct], pr);
      }
    }
  }
}

// ---------------- fused softmax + row-gather aggregation + emb (wave per node) ----------------
template<int H, int MODE, int ACT>
__global__ __launch_bounds__(256) void gat_fused(
    const int* __restrict__ csr_off, const int* __restrict__ src_sorted,
    const int* __restrict__ et_sorted,
    const float* __restrict__ el, const float* __restrict__ er, const float* __restrict__ ee5,
    const float* __restrict__ aprev, float* __restrict__ aout,
    const short* __restrict__ featb, short* __restrict__ outb,
    short* __restrict__ o_b, int kslice){
  const int wid = threadIdx.x >> 6, lane = threadIdx.x & 63;
  const int n = blockIdx.x * 4 + wid;
  if (n >= N_NODES) return;
  constexpr int NC = H * 192 / 8;
  const int c0 = lane, h0 = (c0 / 24) % H;
  const int c1 = lane + 64, h1 = (c1 / 24) % H;
  const bool act0 = (c0 < NC);
  const bool act1 = (H == 4) && (lane < 32);
  const int off = csr_off[n];
  const int cnt = csr_off[n + 1] - off;
  __shared__ float a_s[4][64][H];
  __shared__ float out_s[4][H * 192];
  float acc0[8] = {}, acc1[8] = {};
  float ern[H];
#pragma unroll
  for (int h = 0; h < H; h++) ern[h] = er[n * H + h];

  if (cnt > 0 && cnt <= 64){
    int p = off + lane;
    int sidx = 0, r = 0;
    if (lane < cnt){ sidx = src_sorted[p]; r = et_sorted[p]; }
    float lg[H];
#pragma unroll
    for (int h = 0; h < H; h++) lg[h] = -1e30f;
    if (lane < cnt){
#pragma unroll
      for (int h = 0; h < H; h++){
        float v = el[sidx * H + h] + ern[h] + ee5[r * H + h];
        lg[h] = (v >= 0.f) ? v : 0.2f * v;
      }
    }
    float ap[4] = {};
    if (MODE > 0 && lane < cnt){
#pragma unroll
      for (int q = 0; q < 4; q++) ap[q] = aprev[(size_t)p * 4 + q];
    }
    float av[H];
#pragma unroll
    for (int h = 0; h < H; h++){
      float mh = wave_max(lg[h]);
      float ex = (lane < cnt) ? __expf(lg[h] - mh) : 0.f;
      float sh = wave_sum(ex);
      float a = ex / sh;
      if (MODE == 1) a = 0.95f * a + 0.05f * ap[h];
      if (MODE == 2) a = 0.95f * a + 0.0125f * (ap[0] + ap[1] + ap[2] + ap[3]);
      av[h] = a;
      if (lane < cnt) a_s[wid][lane][h] = a;
    }
    if (MODE != 2 && lane < cnt){
      f32x4 o = {av[0], av[1], av[2], av[3]};
      *(f32x4*)(aout + (size_t)p * 4) = o;
    }
    int b = 0;
    for (; b + 4 <= cnt; b += 4){
      int p4 = off + b;
      int s0 = src_sorted[p4],     s1 = src_sorted[p4 + 1];
      int s2 = src_sorted[p4 + 2], s3 = src_sorted[p4 + 3];
      s16x8 v00, v01, v02, v03, v10, v11, v12, v13;
      if (act0){
        v00 = *(const s16x8*)(featb + (size_t)s0 * (H * 192) + c0 * 8);
        v01 = *(const s16x8*)(featb + (size_t)s1 * (H * 192) + c0 * 8);
        v02 = *(const s16x8*)(featb + (size_t)s2 * (H * 192) + c0 * 8);
        v03 = *(const s16x8*)(featb + (size_t)s3 * (H * 192) + c0 * 8);
      }
      if (act1){
        v10 = *(const s16x8*)(featb + (size_t)s0 * (H * 192) + c1 * 8);
        v11 = *(const s16x8*)(featb + (size_t)s1 * (H * 192) + c1 * 8);
        v12 = *(const s16x8*)(featb + (size_t)s2 * (H * 192) + c1 * 8);
        v13 = *(const s16x8*)(featb + (size_t)s3 * (H * 192) + c1 * 8);
      }
      if (act0){
        float a0 = a_s[wid][b][h0], a1 = a_s[wid][b + 1][h0];
        float a2 = a_s[wid][b + 2][h0], a3 = a_s[wid][b + 3][h0];
#pragma unroll
        for (int i = 0; i < 8; i++)
          acc0[i] += a0 * bf2f(v00[i]) + a1 * bf2f(v01[i]) +
                     a2 * bf2f(v02[i]) + a3 * bf2f(v03[i]);
      }
      if (act1){
        float a0 = a_s[wid][b][h1], a1 = a_s[wid][b + 1][h1];
        float a2 = a_s[wid][b + 2][h1], a3 = a_s[wid][b + 3][h1];
#pragma unroll
        for (int i = 0; i < 8; i++)
          acc1[i] += a0 * bf2f(v10[i]) + a1 * bf2f(v11[i]) +
                     a2 * bf2f(v12[i]) + a3 * bf2f(v13[i]);
      }
    }
    for (; b < cnt; b++){
      int pp = off + b;
      int s = src_sorted[pp];
      if (act0){
        float a = a_s[wid][b][h0];
        s16x8 v = *(const s16x8*)(featb + (size_t)s * (H * 192) + c0 * 8);
#pragma unroll
        for (int i = 0; i < 8; i++) acc0[i] += a * bf2f(v[i]);
      }
      if (act1){
        float a = a_s[wid][b][h1];
        s16x8 v = *(const s16x8*)(featb + (size_t)s * (H * 192) + c1 * 8);
#pragma unroll
        for (int i = 0; i < 8; i++) acc1[i] += a * bf2f(v[i]);
      }
    }
  } else if (cnt > 64){
    float mh[H], sh[H];
#pragma unroll
    for (int h = 0; h < H; h++){ mh[h] = -1e30f; sh[h] = 0.f; }
    for (int b = lane; b < cnt; b += 64){
      int p = off + b; int s = src_sorted[p]; int r = et_sorted[p];
#pragma unroll
      for (int h = 0; h < H; h++){
        float v = el[s * H + h] + ern[h] + ee5[r * H + h];
        v = (v >= 0.f) ? v : 0.2f * v;
        mh[h] = fmaxf(mh[h], v);
      }
    }
#pragma unroll
    for (int h = 0; h < H; h++) mh[h] = wave_max(mh[h]);
    for (int b = lane; b < cnt; b += 64){
      int p = off + b; int s = src_sorted[p]; int r = et_sorted[p];
#pragma unroll
      for (int h = 0; h < H; h++){
        float v = el[s * H + h] + ern[h] + ee5[r * H + h];
        v = (v >= 0.f) ? v : 0.2f * v;
        sh[h] += __expf(v - mh[h]);
      }
    }
#pragma unroll
    for (int h = 0; h < H; h++) sh[h] = wave_sum(sh[h]);
    if (MODE != 2){
      for (int b = lane; b < cnt; b += 64){
        int p = off + b; int s = src_sorted[p]; int r = et_sorted[p];
        float ap[4] = {};
        if (MODE > 0){
#pragma unroll
          for (int q = 0; q < 4; q++) ap[q] = aprev[(size_t)p * 4 + q];
        }
        float av[4] = {};
#pragma unroll
        for (int h = 0; h < H; h++){
          float v = el[s * H + h] + ern[h] + ee5[r * H + h];
          v = (v >= 0.f) ? v : 0.2f * v;
          float a = __expf(v - mh[h]) / sh[h];
          if (MODE == 1) a = 0.95f * a + 0.05f * ap[h];
          av[h] = a;
        }
        f32x4 o = {av[0], av[1], av[2], av[3]};
        *(f32x4*)(aout + (size_t)p * 4) = o;
      }
    }
    for (int b = 0; b < cnt; b++){
      int p = off + b; int s = src_sorted[p]; int r = et_sorted[p];
      const short* row = featb + (size_t)s * (H * 192);
      float apm[4] = {};
      if (MODE > 0){
#pragma unroll
        for (int q = 0; q < 4; q++) apm[q] = aprev[(size_t)p * 4 + q];
      }
      if (act0){
        float v = el[s * H + h0] + ern[h0] + ee5[r * H + h0];
        v = (v >= 0.f) ? v : 0.2f * v;
        float a = __expf(v - mh[h0]) / sh[h0];
        if (MODE == 1) a = 0.95f * a + 0.05f * apm[h0];
        if (MODE == 2) a = 0.95f * a + 0.0125f * (apm[0] + apm[1] + apm[2] + apm[3]);
        s16x8 vv = *(const s16x8*)(row + c0 * 8);
#pragma unroll
        for (int i = 0; i < 8; i++) acc0[i] += a * bf2f(vv[i]);
      }
      if (act1){
        float v = el[s * H + h1] + ern[h1] + ee5[r * H + h1];
        v = (v >= 0.f) ? v : 0.2f * v;
        float a = __expf(v - mh[h1]) / sh[h1];
        if (MODE == 1) a = 0.95f * a + 0.05f * apm[h1];
        s16x8 vv = *(const s16x8*)(row + c1 * 8);
#pragma unroll
        for (int i = 0; i < 8; i++) acc1[i] += a * bf2f(vv[i]);
      }
    }
  }
  // ---- epilogue ----
  if (act0){
    int dd = c0 * 8, h = dd / 192, rr = dd % 192, t = rr / 64, j = rr % 64;
    if (ACT){
#pragma unroll
      for (int i = 0; i < 8; i++) acc0[i] = (acc0[i] > 0.f) ? acc0[i] : expm1f(acc0[i]);
    }
#pragma unroll
    for (int i = 0; i < 8; i++) out_s[wid][dd + i] = acc0[i];
    if (outb){
      s16x8 o;
#pragma unroll
      for (int i = 0; i < 8; i++) o[i] = f2bf(acc0[i]);
      *(s16x8*)(outb + ((size_t)(t * NPAD) + n) * 256 + h * 64 + j) = o;
    }
  }
  if (act1){
    int dd = c1 * 8, h = dd / 192, rr = dd % 192, t = rr / 64, j = rr % 64;
    if (ACT){
#pragma unroll
      for (int i = 0; i < 8; i++) acc1[i] = (acc1[i] > 0.f) ? acc1[i] : expm1f(acc1[i]);
    }
#pragma unroll
    for (int i = 0; i < 8; i++) out_s[wid][dd + i] = acc1[i];
    if (outb){
      s16x8 o;
#pragma unroll
      for (int i = 0; i < 8; i++) o[i] = f2bf(acc1[i]);
      *(s16x8*)(outb + ((size_t)(t * NPAD) + n) * 256 + h * 64 + j) = o;
    }
  }
  for (int t = 0; t < 3; t++){
    float v;
    if (H == 4)
      v = 0.25f * (out_s[wid][t * 64 + lane] + out_s[wid][192 + t * 64 + lane] +
                   out_s[wid][384 + t * 64 + lane] + out_s[wid][576 + t * 64 + lane]);
    else
      v = out_s[wid][t * 64 + lane];
    float ss = wave_sum(v * v);
    float sc = 1.f / fmaxf(sqrtf(ss), 1e-12f);
    o_b[(size_t)n * 768 + t * 256 + kslice * 64 + lane] = f2bf(v * sc);
  }
}

// ---------------- DistMult via MFMA ----------------
__global__ void distmult_mfma(const short* __restrict__ o_b, const short* __restrict__ Mt,
                              const int* __restrict__ pairs, const int* __restrict__ left,
                              const int* __restrict__ right, const int* __restrict__ mid,
                              float* __restrict__ score){
  const int pt = blockIdx.x, ct = blockIdx.y;
  const int tid = threadIdx.x;
  const int w = tid >> 6, lane = tid & 63;
  const int quad = lane >> 4, ln = lane & 15;
  __shared__ __attribute__((aligned(16))) short smem[8192];
  short* A_s = smem;
  short* B_s = smem + 2048;
  __shared__ int pid_s[64];
  __shared__ int lbase[64];
  if (tid < 64){
    int p = pairs[pt * 64 + tid];
    pid_s[tid] = p;
    lbase[tid] = (p >= 0) ? left[p] * 768 : 0;
  }
  __syncthreads();
  int p0 = pid_s[0];
  if (p0 < 0) return;
  const int r = mid[p0];
  const short* Mr = Mt + (size_t)r * 768 * 768;
  f32x4 acc[8] = {};
  for (int kk = 0; kk < 768; kk += 32){
    {
      int row = tid >> 2, chunk = tid & 3;
      s16x8 v = *(const s16x8*)(o_b + (size_t)lbase[row] + kk + chunk * 8);
      *(s16x8*)(A_s + row * 32 + chunk * 8) = v;
    }
    {
      int row = tid >> 1, half = tid & 1;
      const s16x8* g = (const s16x8*)(Mr + (size_t)(ct * 128 + row) * 768 + kk + half * 16);
      s16x8 v0 = g[0], v1 = g[1];
      *(s16x8*)(B_s + row * 32 + half * 16) = v0;
      *(s16x8*)(B_s + row * 32 + half * 16 + 8) = v1;
    }
    __syncthreads();
    s16x8 af = *(s16x8*)(A_s + (w * 16 + ln) * 32 + quad * 8);
#pragma unroll
    for (int b = 0; b < 8; b++){
      s16x8 bf = *(s16x8*)(B_s + (b * 16 + ln) * 32 + quad * 8);
      acc[b] = __builtin_amdgcn_mfma_f32_16x16x32_bf16(af, bf, acc[b], 0, 0, 0);
    }
    __syncthreads();
  }
  short* RE_s = smem;
  {
    int row = tid >> 2, quarter = tid & 3;
    int p = pid_s[row];
    s16x8 v0 = {}, v1 = {}, v2 = {}, v3 = {};
    if (p >= 0){
      const s16x8* g = (const s16x8*)(o_b + (size_t)right[p] * 768 + ct * 128 + quarter * 32);
      v0 = g[0]; v1 = g[1]; v2 = g[2]; v3 = g[3];
    }
    __syncthreads();
    short* dst = RE_s + row * 128 + quarter * 32;
    *(s16x8*)(dst)      = v0;
    *(s16x8*)(dst + 8)  = v1;
    *(s16x8*)(dst + 16) = v2;
    *(s16x8*)(dst + 24) = v3;
  }
  __syncthreads();
#pragma unroll
  for (int i = 0; i < 4; i++){
    int row = w * 16 + quad * 4 + i;
    float s = 0.f;
#pragma unroll
    for (int b = 0; b < 8; b++)
      s += acc[b][i] * bf2f(RE_s[row * 128 + b * 16 + ln]);
    s += __shfl_xor(s, 1); s += __shfl_xor(s, 2);
    s += __shfl_xor(s, 4); s += __shfl_xor(s, 8);
    if (ln == 0){
      int p = pid_s[row];
      if (p >= 0) atomicAdd(&score[p], s);
    }
  }
}

__global__ void sigmoid_k(const float* __restrict__ score, float* __restrict__ out){
  int i = blockIdx.x * 256 + threadIdx.x;
  if (i < N_PAIRS) out[i] = 1.f / (1.f + __expf(-score[i]));
}

// ---------------- launcher ----------------
extern "C" void kernel_launch(void* const* d_in, const int* in_sizes, int n_in,
                              void* d_out, int out_size, void* d_ws, size_t ws_size,
                              hipStream_t stream){
  const float* f0 = (const float*)d_in[0];
  const float* w0 = (const float*)d_in[1];
  const float* b0 = (const float*)d_in[2];
  const float* f1 = (const float*)d_in[3];
  const float* w1 = (const float*)d_in[4];
  const float* b1 = (const float*)d_in[5];
  const float* f2 = (const float*)d_in[6];
  const float* w2_ = (const float*)d_in[7];
  const float* b2 = (const float*)d_in[8];
  const float* lW[3]  = {(const float*)d_in[9],  (const float*)d_in[15], (const float*)d_in[21]};
  const float* lal[3] = {(const float*)d_in[10], (const float*)d_in[16], (const float*)d_in[22]};
  const float* lar[3] = {(const float*)d_in[11], (const float*)d_in[17], (const float*)d_in[23]};
  const float* lee[3] = {(const float*)d_in[12], (const float*)d_in[18], (const float*)d_in[24]};
  const float* lwe[3] = {(const float*)d_in[13], (const float*)d_in[19], (const float*)d_in[25]};
  const float* lae[3] = {(const float*)d_in[14], (const float*)d_in[20], (const float*)d_in[26]};
  const float* dmW = (const float*)d_in[27];
  const int* efeat = (const int*)d_in[28];
  const int* srcv  = (const int*)d_in[29];
  const int* dstv  = (const int*)d_in[30];
  const int* left  = (const int*)d_in[31];
  const int* right = (const int*)d_in[32];
  const int* midv  = (const int*)d_in[33];
  float* out = (float*)d_out;

  // ---- workspace layout ----
  short* feat_b = (short*)d_ws;               // 15,360,000 shorts
  float* aA     = (float*)(feat_b + 15360000);// 800,000
  float* aB     = aA + 800000;                // 800,000
  float* eall   = aB + 800000;                // 480,000
  float* ee5f   = eall + 480000;              // 96
  float* score  = ee5f + 96;                  // 10,016
  int* csr_cnt  = (int*)(score + 10016);      // 20,000
  int* csr_off  = csr_cnt + 20000;            // 20,004
  int* csr_pos  = csr_off + 20004;            // 320,000 (padded x16)
  int* loc      = csr_pos + 320000;           // 20,000
  int* bsum     = loc + 20000;                // 128
  int* bofs     = bsum + 128;                 // 128
  int* src_sorted = bofs + 128;               // 200,000
  int* et_sorted  = src_sorted + 200000;      // 200,000
  int* cnt5     = et_sorted + 200000;         // 80
  int* off5     = cnt5 + 80;                  // 8
  int* pos5     = off5 + 8;                   // 80
  int* pairs    = pos5 + 80;                  // 10,368
  short* o_b    = (short*)(pairs + PAIR_PAD); // 15,360,000
  short* Xb0    = o_b + 15360000;             // 3,858,432
  short* Xb12   = Xb0 + 3858432;              // 15,433,728
  short* Wt0    = Xb12 + 15433728;            // 49,152
  short* Wt1    = Wt0 + 49152;                // 196,608
  short* Wt2    = Wt1 + 196608;               // 49,152
  short* Mt     = Wt2 + 49152;                // 2,949,120
  float* elf0 = eall, *erf0 = eall + 80000;
  float* elf1 = eall + 160000, *erf1 = eall + 240000;
  float* elf2 = eall + 320000, *erf2 = eall + 400000;

  build_h<<<2500, 64, 0, stream>>>(f0, w0, b0, f1, w1, b1, f2, w2_, b2, Xb0, o_b,
                                   csr_cnt, cnt5, pos5, score, pairs, eall, Xb12, feat_b);
  count_prep_k<<<782 + 6336, 256, 0, stream>>>(dstv, csr_cnt, midv, cnt5,
                                               lW[0], lW[1], lW[2], dmW, Wt0, Wt1, Wt2, Mt,
                                               lee[0], lwe[0], lae[0], lee[1], lwe[1], lae[1],
                                               lee[2], lwe[2], lae[2], ee5f);
  scan1_k<<<NBLK, 256, 0, stream>>>(csr_cnt, loc, bsum);
  scan2_k<<<1, 128, 0, stream>>>(bsum, bofs, cnt5, off5);
  scan3_k<<<NBLK, 256, 0, stream>>>(loc, bofs, csr_off, csr_pos);
  scatter_k<<<782, 256, 0, stream>>>(dstv, srcv, efeat, csr_pos, src_sorted, et_sorted,
                                     midv, off5, pos5, pairs);

  // layer 0 (H=4, typed proj tiles, ELU) -> emb slice 1
  { dim3 g(64, 4, 3);
    mfma_proj<64, 256, 1><<<g, 256, 0, stream>>>(Xb0, Wt0, feat_b, lal[0], lar[0], elf0, erf0); }
  gat_fused<4, 0, 1><<<5000, 256, 0, stream>>>(csr_off, src_sorted, et_sorted, elf0, erf0, ee5f,
                                               nullptr, aA, feat_b, Xb12, o_b, 1);

  // layer 1 (H=4, residual aA, ELU) -> emb slice 2
  { dim3 g(NPAD / 128, 4, 3);
    mfma_proj<256, 256, 0><<<g, 256, 0, stream>>>(Xb12, Wt1, feat_b, lal[1], lar[1], elf1, erf1); }
  gat_fused<4, 1, 1><<<5000, 256, 0, stream>>>(csr_off, src_sorted, et_sorted, elf1, erf1, ee5f + 32,
                                               aA, aB, feat_b, Xb12, o_b, 2);

  // layer 2 (H=1, blend vs mean of a1, no activation) -> emb slice 3
  { dim3 g(NPAD / 128, 1, 3);
    mfma_proj<256, 64, 0><<<g, 256, 0, stream>>>(Xb12, Wt2, feat_b, lal[2], lar[2], elf2, erf2); }
  gat_fused<1, 2, 0><<<5000, 256, 0, stream>>>(csr_off, src_sorted, et_sorted, elf2, erf2, ee5f + 64,
                                               aB, nullptr, feat_b, nullptr, o_b, 3);

  // DistMult + sigmoid
  { dim3 g(DM_TILES, 6); distmult_mfma<<<g, 256, 0, stream>>>(o_b, Mt, pairs, left, right, midv, score); }
  sigmoid_k<<<40, 256, 0, stream>>>(score, out);
}